// Round 5
// baseline (1898.654 us; speedup 1.0000x reference)
//
#include <hip/hip_runtime.h>
#include <hip/hip_bf16.h>
#include <stdint.h>

#define BATCH   8
#define NPTS    4096
#define DCH     64
#define NPOINT  1024
#define NSAMPLE 32
#define NEWXYZ_FLOATS (BATCH * NPOINT * 3)

typedef float v2f __attribute__((ext_vector_type(2)));

__device__ __forceinline__ float sqdist_rn(float px, float py, float pz,
                                           float cx, float cy, float cz) {
    // Matches numpy order: ((dx*dx + dy*dy) + dz*dz), round-to-nearest each op, NO fma
    float dx = __fsub_rn(px, cx);
    float dy = __fsub_rn(py, cy);
    float dz = __fsub_rn(pz, cz);
    return __fadd_rn(__fadd_rn(__fmul_rn(dx, dx), __fmul_rn(dy, dy)), __fmul_rn(dz, dz));
}

__device__ __forceinline__ unsigned long long ullmax(unsigned long long a, unsigned long long b) {
    return a > b ? a : b;
}

// ---------------- prep: transpose weights, fold BN ----------------
__global__ void prep_kernel(const float* __restrict__ w0, const float* __restrict__ b0,
                            const float* __restrict__ g0, const float* __restrict__ be0,
                            const float* __restrict__ m0, const float* __restrict__ v0,
                            const float* __restrict__ w1, const float* __restrict__ b1,
                            const float* __restrict__ g1, const float* __restrict__ be1,
                            const float* __restrict__ m1, const float* __restrict__ v1,
                            const float* __restrict__ w2, const float* __restrict__ b2,
                            const float* __restrict__ g2, const float* __restrict__ be2,
                            const float* __restrict__ m2, const float* __restrict__ v2,
                            float* __restrict__ wT0, float* __restrict__ wT1,
                            float* __restrict__ wT2, float* __restrict__ st) {
    const int tid  = blockIdx.x * blockDim.x + threadIdx.x;
    const int nthr = gridDim.x * blockDim.x;
    for (int i = tid; i < 64 * 67; i += nthr) { int o = i / 67, c = i % 67; wT0[c * 64 + o] = w0[i]; }
    for (int i = tid; i < 64 * 64; i += nthr) { int o = i >> 6, c = i & 63; wT1[c * 64 + o] = w1[i]; }
    for (int i = tid; i < 128 * 64; i += nthr) { int o = i >> 6, c = i & 63; wT2[c * 128 + o] = w2[i]; }
    if (tid < 64) {
        float s = g0[tid] / sqrtf(v0[tid] + 1e-5f);
        st[tid] = s;
        st[64 + tid] = (b0[tid] - m0[tid]) * s + be0[tid];
        s = g1[tid] / sqrtf(v1[tid] + 1e-5f);
        st[128 + tid] = s;
        st[192 + tid] = (b1[tid] - m1[tid]) * s + be1[tid];
    }
    if (tid < 128) {
        float s = g2[tid] / sqrtf(v2[tid] + 1e-5f);
        st[256 + tid] = s;
        st[384 + tid] = (b2[tid] - m2[tid]) * s + be2[tid];
    }
}

// ---------------- FPS: 4 blocks x 256 thr; 2 batches per block, pipelined ----------------
#define FPS_RED(CTRL)                                                              \
        {                                                                          \
            int t_ = __builtin_amdgcn_update_dpp(0, mb, CTRL, 0xF, 0xF, true);     \
            mb = __float_as_int(fmaxf(__int_as_float(mb), __int_as_float(t_)));    \
        }

// dist+reduce+key-write for one batch (16 pts/lane). Bit-exact chain preserved.
__device__ __forceinline__ void fps_phase(float (&dd)[16],
                                          const v2f (&px)[8], const v2f (&py)[8],
                                          const v2f (&pz)[8],
                                          float cx, float cy, float cz,
                                          unsigned long long* wkeyW,
                                          int lane, int wid) {
    const v2f ncx = {-cx, -cx}, ncy = {-cy, -cy}, ncz = {-cz, -cz};
#pragma unroll
    for (int k = 0; k < 8; ++k) {
        v2f dx, dy, dz, qx, qy, qz, s1, s2;
        asm("v_pk_add_f32 %0, %1, %2" : "=v"(dx) : "v"(px[k]), "v"(ncx));
        asm("v_pk_add_f32 %0, %1, %2" : "=v"(dy) : "v"(py[k]), "v"(ncy));
        asm("v_pk_add_f32 %0, %1, %2" : "=v"(dz) : "v"(pz[k]), "v"(ncz));
        asm("v_pk_mul_f32 %0, %1, %1" : "=v"(qx) : "v"(dx));
        asm("v_pk_mul_f32 %0, %1, %1" : "=v"(qy) : "v"(dy));
        asm("v_pk_mul_f32 %0, %1, %1" : "=v"(qz) : "v"(dz));
        asm("v_pk_add_f32 %0, %1, %2" : "=v"(s1) : "v"(qx), "v"(qy));
        asm("v_pk_add_f32 %0, %1, %2" : "=v"(s2) : "v"(s1), "v"(qz));
        dd[2 * k]     = fminf(dd[2 * k],     s2[0]);
        dd[2 * k + 1] = fminf(dd[2 * k + 1], s2[1]);
    }
    // per-lane max over 16 slots
    float m = fmaxf(fmaxf(fmaxf(fmaxf(dd[0], dd[1]), fmaxf(dd[2], dd[3])),
                          fmaxf(fmaxf(dd[4], dd[5]), fmaxf(dd[6], dd[7]))),
                    fmaxf(fmaxf(fmaxf(dd[8], dd[9]), fmaxf(dd[10], dd[11])),
                          fmaxf(fmaxf(dd[12], dd[13]), fmaxf(dd[14], dd[15]))));
    // wave max -> lane 63 (pure-VALU DPP; values >= 0 so 0-fill is identity)
    int mb = __float_as_int(m);
    FPS_RED(0x111)  // row_shr:1
    FPS_RED(0x112)  // row_shr:2
    FPS_RED(0x114)  // row_shr:4
    FPS_RED(0x118)  // row_shr:8
    FPS_RED(0x142)  // row_bcast:15
    FPS_RED(0x143)  // row_bcast:31
    const unsigned Mb = (unsigned)__builtin_amdgcn_readlane(mb, 63);
    // first index attaining the max: per-slot ballot (VALU) + scalar select chain
    unsigned jw = 0xFFFFFFFFu;
#pragma unroll
    for (int i = 15; i >= 0; --i) {
        const unsigned long long msk = __ballot(__float_as_uint(dd[i]) == Mb);
        if (msk) jw = (unsigned)(i * 256 + (wid << 6)) + (unsigned)__builtin_ctzll(msk);
    }
    if (lane == 0)
        wkeyW[wid] = ((unsigned long long)Mb << 32) | (unsigned long long)(0xFFFFFFFFu - jw);
}

__device__ __forceinline__ void fps_combine(const unsigned long long* wkeyR,
                                            const float4* sxyz,
                                            float& cx, float& cy, float& cz) {
    const ulonglong2* wk = (const ulonglong2*)wkeyR;
    const ulonglong2 a = wk[0], b = wk[1];
    const unsigned long long v = ullmax(ullmax(a.x, a.y), ullmax(b.x, b.y));
    const unsigned widx = 0xFFFFFFFFu - (unsigned)(v & 0xFFFFFFFFull);
    const float4 c = sxyz[widx];
    cx = c.x; cy = c.y; cz = c.z;
}

__global__ __launch_bounds__(256, 1) void fps_kernel(const float* __restrict__ xyz,
                                                     float* __restrict__ newxyz) {
    __shared__ float4 sxyzA[NPTS];                     // 64 KB
    __shared__ float4 sxyzB[NPTS];                     // 64 KB
    __shared__ __align__(16) unsigned long long wkeyA[2][4];
    __shared__ __align__(16) unsigned long long wkeyB[2][4];
    const int tid  = threadIdx.x;
    const int lane = tid & 63;
    const int wid  = tid >> 6;
    const int bA   = 2 * blockIdx.x;
    const int bB   = bA + 1;
    const float* xbA = xyz + (size_t)bA * NPTS * 3;
    const float* xbB = xyz + (size_t)bB * NPTS * 3;
    float* outA = newxyz + (size_t)bA * NPOINT * 3;
    float* outB = newxyz + (size_t)bB * NPOINT * 3;

    v2f pxA[8], pyA[8], pzA[8], pxB[8], pyB[8], pzB[8];
    float ddA[16], ddB[16];
#pragma unroll
    for (int i = 0; i < 16; ++i) {
        const int p = tid + i * 256;
        {
            const float x = xbA[3 * p], y = xbA[3 * p + 1], z = xbA[3 * p + 2];
            sxyzA[p] = make_float4(x, y, z, 0.f);
            pxA[i >> 1][i & 1] = x; pyA[i >> 1][i & 1] = y; pzA[i >> 1][i & 1] = z;
            ddA[i] = 1e10f;
        }
        {
            const float x = xbB[3 * p], y = xbB[3 * p + 1], z = xbB[3 * p + 2];
            sxyzB[p] = make_float4(x, y, z, 0.f);
            pxB[i >> 1][i & 1] = x; pyB[i >> 1][i & 1] = y; pzB[i >> 1][i & 1] = z;
            ddB[i] = 1e10f;
        }
    }
    float cxA = xbA[0], cyA = xbA[1], czA = xbA[2];
    float cxB = xbB[0], cyB = xbB[1], czB = xbB[2];
    if (tid == 0) {
        outA[0] = cxA; outA[1] = cyA; outA[2] = czA;
        outB[0] = cxB; outB[1] = cyB; outB[2] = czB;
    }
    __syncthreads();

    // Pipelined schedule: per iteration t, phase1 = A-dist + B-combine(t-1),
    // phase2 = B-dist + A-combine(t). Each LDS key buffer crosses exactly one
    // barrier between write and read; t&1 double-buffering prevents overwrite.
    for (int t = 1; t < NPOINT; ++t) {
        fps_phase(ddA, pxA, pyA, pzA, cxA, cyA, czA, &wkeyA[t & 1][0], lane, wid);
        if (t > 1) {
            fps_combine(&wkeyB[(t - 1) & 1][0], sxyzB, cxB, cyB, czB);
            if (tid == 0) {
                float* o = outB + (size_t)(t - 1) * 3;
                o[0] = cxB; o[1] = cyB; o[2] = czB;
            }
        }
        __syncthreads();
        fps_phase(ddB, pxB, pyB, pzB, cxB, cyB, czB, &wkeyB[t & 1][0], lane, wid);
        fps_combine(&wkeyA[t & 1][0], sxyzA, cxA, cyA, czA);
        if (tid == 0) {
            float* o = outA + (size_t)t * 3;
            o[0] = cxA; o[1] = cyA; o[2] = czA;
        }
        __syncthreads();
    }
    // epilogue: B's final selection
    fps_combine(&wkeyB[(NPOINT - 1) & 1][0], sxyzB, cxB, cyB, czB);
    if (tid == 0) {
        float* o = outB + (size_t)(NPOINT - 1) * 3;
        o[0] = cxB; o[1] = cyB; o[2] = czB;
    }
}

// ---------------- ball query: one wave per query ----------------
__global__ __launch_bounds__(256) void ballq_kernel(const float* __restrict__ xyz,
                                                    const float* __restrict__ newxyz,
                                                    int* __restrict__ gidx) {
    __shared__ int g[4][NSAMPLE];
    const int lane = threadIdx.x & 63;
    const int w    = threadIdx.x >> 6;
    const int q    = blockIdx.x * 4 + w;   // b*1024 + s
    const int b    = q >> 10;
    const float* xb = xyz + (size_t)b * NPTS * 3;
    const float* c  = newxyz + (size_t)q * 3;
    const float cx = c[0], cy = c[1], cz = c[2];
    const float r2 = 0.04f;

    int cnt = 0;
    for (int base = 0; base < NPTS; base += 64) {
        const int j = base + lane;
        const float d = sqdist_rn(xb[j * 3 + 0], xb[j * 3 + 1], xb[j * 3 + 2], cx, cy, cz);
        const bool keep = !(d > r2);
        const unsigned long long m = __ballot(keep);
        if (keep) {
            const int slot = cnt + __popcll(m & ((1ull << lane) - 1ull));
            if (slot < NSAMPLE) g[w][slot] = j;
        }
        cnt += (int)__popcll(m);
        if (cnt >= NSAMPLE) break;
    }
    __syncthreads();
    const int first = g[w][0];   // at least the center point itself is within radius
    if (lane < NSAMPLE) {
        const int v = (lane < cnt) ? g[w][lane] : first;
        gidx[(size_t)q * NSAMPLE + lane] = v;
    }
}

// ---------------- grouped MLP + maxpool: one wave per query ----------------
__global__ __launch_bounds__(256) void mlp_kernel(
    const float* __restrict__ xyz, const float* __restrict__ points,
    const float* __restrict__ newxyz, const int* __restrict__ gidx,
    const float* __restrict__ wT0, const float* __restrict__ wT1,
    const float* __restrict__ wT2, const float* __restrict__ st,
    float* __restrict__ outp) {
    __shared__ float Xs[4][68][36];   // per-wave x, channel-major [c][k]
    const int lane = threadIdx.x & 63;
    const int w    = threadIdx.x >> 6;
    const int q    = blockIdx.x * 4 + w;
    const int b    = q >> 10;
    float (*X)[36] = Xs[w];
    const int* gi = gidx + (size_t)q * NSAMPLE;
    const float* nc = newxyz + (size_t)q * 3;
    const float c0 = nc[0], c1 = nc[1], c2 = nc[2];

    // gather: lane = channel, loop over samples; points row is 256B coalesced
    for (int k = 0; k < NSAMPLE; ++k) {
        const int idx = gi[k];
        X[3 + lane][k] = points[((size_t)b * NPTS + idx) * DCH + lane];
        if (lane < 3) {
            const float cv = (lane == 0) ? c0 : ((lane == 1) ? c1 : c2);
            X[lane][k] = xyz[((size_t)b * NPTS + idx) * 3 + lane] - cv;
        }
    }

    const int kk = lane >> 3;  // 4-sample tile
    const int oo = lane & 7;   // 8-out-channel tile

    // ---- layer 0: 67 -> 64
    float acc[4][8];
#pragma unroll
    for (int i = 0; i < 4; ++i)
#pragma unroll
        for (int j = 0; j < 8; ++j) acc[i][j] = 0.f;

    for (int c = 0; c < 67; ++c) {
        const float4 xv = *reinterpret_cast<const float4*>(&X[c][4 * kk]);
        const float4 wa = *reinterpret_cast<const float4*>(&wT0[c * 64 + 8 * oo]);
        const float4 wb = *reinterpret_cast<const float4*>(&wT0[c * 64 + 8 * oo + 4]);
        const float xr[4] = {xv.x, xv.y, xv.z, xv.w};
        const float wr[8] = {wa.x, wa.y, wa.z, wa.w, wb.x, wb.y, wb.z, wb.w};
#pragma unroll
        for (int i = 0; i < 4; ++i)
#pragma unroll
            for (int j = 0; j < 8; ++j)
                acc[i][j] = fmaf(xr[i], wr[j], acc[i][j]);
    }
    {
        const float4 sa = *reinterpret_cast<const float4*>(&st[8 * oo]);
        const float4 sb = *reinterpret_cast<const float4*>(&st[8 * oo + 4]);
        const float4 ta = *reinterpret_cast<const float4*>(&st[64 + 8 * oo]);
        const float4 tb = *reinterpret_cast<const float4*>(&st[64 + 8 * oo + 4]);
        const float sr[8] = {sa.x, sa.y, sa.z, sa.w, sb.x, sb.y, sb.z, sb.w};
        const float tr[8] = {ta.x, ta.y, ta.z, ta.w, tb.x, tb.y, tb.z, tb.w};
#pragma unroll
        for (int j = 0; j < 8; ++j) {
            float4 v;
            v.x = fmaxf(fmaf(acc[0][j], sr[j], tr[j]), 0.f);
            v.y = fmaxf(fmaf(acc[1][j], sr[j], tr[j]), 0.f);
            v.z = fmaxf(fmaf(acc[2][j], sr[j], tr[j]), 0.f);
            v.w = fmaxf(fmaf(acc[3][j], sr[j], tr[j]), 0.f);
            *reinterpret_cast<float4*>(&X[8 * oo + j][4 * kk]) = v;
        }
    }

    // ---- layer 1: 64 -> 64
#pragma unroll
    for (int i = 0; i < 4; ++i)
#pragma unroll
        for (int j = 0; j < 8; ++j) acc[i][j] = 0.f;

    for (int c = 0; c < 64; ++c) {
        const float4 xv = *reinterpret_cast<const float4*>(&X[c][4 * kk]);
        const float4 wa = *reinterpret_cast<const float4*>(&wT1[c * 64 + 8 * oo]);
        const float4 wb = *reinterpret_cast<const float4*>(&wT1[c * 64 + 8 * oo + 4]);
        const float xr[4] = {xv.x, xv.y, xv.z, xv.w};
        const float wr[8] = {wa.x, wa.y, wa.z, wa.w, wb.x, wb.y, wb.z, wb.w};
#pragma unroll
        for (int i = 0; i < 4; ++i)
#pragma unroll
            for (int j = 0; j < 8; ++j)
                acc[i][j] = fmaf(xr[i], wr[j], acc[i][j]);
    }
    {
        const float4 sa = *reinterpret_cast<const float4*>(&st[128 + 8 * oo]);
        const float4 sb = *reinterpret_cast<const float4*>(&st[128 + 8 * oo + 4]);
        const float4 ta = *reinterpret_cast<const float4*>(&st[192 + 8 * oo]);
        const float4 tb = *reinterpret_cast<const float4*>(&st[192 + 8 * oo + 4]);
        const float sr[8] = {sa.x, sa.y, sa.z, sa.w, sb.x, sb.y, sb.z, sb.w};
        const float tr[8] = {ta.x, ta.y, ta.z, ta.w, tb.x, tb.y, tb.z, tb.w};
#pragma unroll
        for (int j = 0; j < 8; ++j) {
            float4 v;
            v.x = fmaxf(fmaf(acc[0][j], sr[j], tr[j]), 0.f);
            v.y = fmaxf(fmaf(acc[1][j], sr[j], tr[j]), 0.f);
            v.z = fmaxf(fmaf(acc[2][j], sr[j], tr[j]), 0.f);
            v.w = fmaxf(fmaf(acc[3][j], sr[j], tr[j]), 0.f);
            *reinterpret_cast<float4*>(&X[8 * oo + j][4 * kk]) = v;
        }
    }

    // ---- layer 2: 64 -> 128, fused maxpool over k
    float a2[4][16];
#pragma unroll
    for (int i = 0; i < 4; ++i)
#pragma unroll
        for (int j = 0; j < 16; ++j) a2[i][j] = 0.f;

    for (int c = 0; c < 64; ++c) {
        const float4 xv = *reinterpret_cast<const float4*>(&X[c][4 * kk]);
        const float xr[4] = {xv.x, xv.y, xv.z, xv.w};
        float wr[16];
#pragma unroll
        for (int j4 = 0; j4 < 4; ++j4) {
            const float4 wv = *reinterpret_cast<const float4*>(&wT2[c * 128 + 16 * oo + 4 * j4]);
            wr[4 * j4 + 0] = wv.x; wr[4 * j4 + 1] = wv.y;
            wr[4 * j4 + 2] = wv.z; wr[4 * j4 + 3] = wv.w;
        }
#pragma unroll
        for (int i = 0; i < 4; ++i)
#pragma unroll
            for (int j = 0; j < 16; ++j)
                a2[i][j] = fmaf(xr[i], wr[j], a2[i][j]);
    }

    float mx[16];
#pragma unroll
    for (int j = 0; j < 16; ++j) {
        const float sj = st[256 + 16 * oo + j];
        const float tj = st[384 + 16 * oo + j];
        float mm = fmaxf(fmaf(a2[0][j], sj, tj), 0.f);
        mm = fmaxf(mm, fmaxf(fmaf(a2[1][j], sj, tj), 0.f));
        mm = fmaxf(mm, fmaxf(fmaf(a2[2][j], sj, tj), 0.f));
        mm = fmaxf(mm, fmaxf(fmaf(a2[3][j], sj, tj), 0.f));
        mx[j] = mm;
    }
#pragma unroll
    for (int j = 0; j < 16; ++j) {
        mx[j] = fmaxf(mx[j], __shfl_xor(mx[j], 8, 64));
        mx[j] = fmaxf(mx[j], __shfl_xor(mx[j], 16, 64));
        mx[j] = fmaxf(mx[j], __shfl_xor(mx[j], 32, 64));
    }
    if (kk == 0) {
        float* dst = outp + (size_t)q * 128 + 16 * oo;
#pragma unroll
        for (int j4 = 0; j4 < 4; ++j4) {
            float4 v;
            v.x = mx[4 * j4 + 0]; v.y = mx[4 * j4 + 1];
            v.z = mx[4 * j4 + 2]; v.w = mx[4 * j4 + 3];
            *reinterpret_cast<float4*>(&dst[4 * j4]) = v;
        }
    }
}

extern "C" void kernel_launch(void* const* d_in, const int* in_sizes, int n_in,
                              void* d_out, int out_size, void* d_ws, size_t ws_size,
                              hipStream_t stream) {
    const float* xyz    = (const float*)d_in[0];
    const float* points = (const float*)d_in[1];
    const float* w0  = (const float*)d_in[2];
    const float* b0  = (const float*)d_in[3];
    const float* g0  = (const float*)d_in[4];
    const float* be0 = (const float*)d_in[5];
    const float* m0  = (const float*)d_in[6];
    const float* v0  = (const float*)d_in[7];
    const float* w1  = (const float*)d_in[8];
    const float* b1  = (const float*)d_in[9];
    const float* g1  = (const float*)d_in[10];
    const float* be1 = (const float*)d_in[11];
    const float* m1  = (const float*)d_in[12];
    const float* v1  = (const float*)d_in[13];
    const float* w2  = (const float*)d_in[14];
    const float* b2  = (const float*)d_in[15];
    const float* g2  = (const float*)d_in[16];
    const float* be2 = (const float*)d_in[17];
    const float* m2  = (const float*)d_in[18];
    const float* v2  = (const float*)d_in[19];

    float* out = (float*)d_out;
    float* ws  = (float*)d_ws;
    float* wT0 = ws;            // 67*64  = 4288
    float* wT1 = ws + 4288;     // 64*64  = 4096
    float* wT2 = ws + 8384;     // 64*128 = 8192
    float* st  = ws + 16576;    // 512 (s0,t0,s1,t1,s2,t2)
    int*   gidx = (int*)(ws + 17088);  // 8192*32 ints

    prep_kernel<<<dim3(17), dim3(256), 0, stream>>>(w0, b0, g0, be0, m0, v0,
                                                    w1, b1, g1, be1, m1, v1,
                                                    w2, b2, g2, be2, m2, v2,
                                                    wT0, wT1, wT2, st);
    fps_kernel<<<dim3(BATCH / 2), dim3(256), 0, stream>>>(xyz, out);
    ballq_kernel<<<dim3(2048), dim3(256), 0, stream>>>(xyz, out, gidx);
    mlp_kernel<<<dim3(2048), dim3(256), 0, stream>>>(xyz, points, out, gidx,
                                                     wT0, wT1, wT2, st,
                                                     out + NEWXYZ_FLOATS);
}

// Round 7
// 1029.532 us; speedup vs baseline: 1.8442x; 1.8442x over previous
//
#include <hip/hip_runtime.h>
#include <hip/hip_bf16.h>
#include <stdint.h>

#define BATCH   8
#define NPTS    4096
#define DCH     64
#define NPOINT  1024
#define NSAMPLE 32
#define NEWXYZ_FLOATS (BATCH * NPOINT * 3)

typedef float v2f __attribute__((ext_vector_type(2)));

__device__ __forceinline__ float sqdist_rn(float px, float py, float pz,
                                           float cx, float cy, float cz) {
    // Matches numpy order: ((dx*dx + dy*dy) + dz*dz), round-to-nearest each op, NO fma
    float dx = __fsub_rn(px, cx);
    float dy = __fsub_rn(py, cy);
    float dz = __fsub_rn(pz, cz);
    return __fadd_rn(__fadd_rn(__fmul_rn(dx, dx), __fmul_rn(dy, dy)), __fmul_rn(dz, dz));
}

__device__ __forceinline__ unsigned long long ullmax(unsigned long long a, unsigned long long b) {
    return a > b ? a : b;
}

template <int CTRL>
__device__ __forceinline__ unsigned long long dpp_u64(unsigned long long v) {
    int lo = (int)(unsigned)(v & 0xFFFFFFFFull);
    int hi = (int)(unsigned)(v >> 32);
    lo = __builtin_amdgcn_update_dpp(0, lo, CTRL, 0xF, 0xF, true);  // bound_ctrl: OOB -> 0
    hi = __builtin_amdgcn_update_dpp(0, hi, CTRL, 0xF, 0xF, true);
    return ((unsigned long long)(unsigned)hi << 32) | (unsigned)lo;
}

// ---------------- prep: transpose weights (permuted cols for L0/L1), fold BN ----------------
// Column permutation col(o) = (o&7)*8 + (o>>3): lane oo's 8 contiguous columns
// [8oo,8oo+8) hold channels o = oo+8j, making the MLP's LDS X-writes conflict-free.
__global__ void prep_kernel(const float* __restrict__ w0, const float* __restrict__ b0,
                            const float* __restrict__ g0, const float* __restrict__ be0,
                            const float* __restrict__ m0, const float* __restrict__ v0,
                            const float* __restrict__ w1, const float* __restrict__ b1,
                            const float* __restrict__ g1, const float* __restrict__ be1,
                            const float* __restrict__ m1, const float* __restrict__ v1,
                            const float* __restrict__ w2, const float* __restrict__ b2,
                            const float* __restrict__ g2, const float* __restrict__ be2,
                            const float* __restrict__ m2, const float* __restrict__ v2,
                            float* __restrict__ wT0, float* __restrict__ wT1,
                            float* __restrict__ wT2, float* __restrict__ st) {
    const int tid  = blockIdx.x * blockDim.x + threadIdx.x;
    const int nthr = gridDim.x * blockDim.x;
    for (int i = tid; i < 64 * 67; i += nthr) {
        int o = i / 67, c = i % 67;
        wT0[c * 64 + (((o & 7) << 3) | (o >> 3))] = w0[i];
    }
    for (int i = tid; i < 64 * 64; i += nthr) {
        int o = i >> 6, c = i & 63;
        wT1[c * 64 + (((o & 7) << 3) | (o >> 3))] = w1[i];
    }
    for (int i = tid; i < 128 * 64; i += nthr) { int o = i >> 6, c = i & 63; wT2[c * 128 + o] = w2[i]; }
    if (tid < 64) {
        const int col = ((tid & 7) << 3) | (tid >> 3);
        float s = g0[tid] / sqrtf(v0[tid] + 1e-5f);
        st[col] = s;
        st[64 + col] = (b0[tid] - m0[tid]) * s + be0[tid];
        s = g1[tid] / sqrtf(v1[tid] + 1e-5f);
        st[128 + col] = s;
        st[192 + col] = (b1[tid] - m1[tid]) * s + be1[tid];
    }
    if (tid < 128) {
        float s = g2[tid] / sqrtf(v2[tid] + 1e-5f);
        st[256 + tid] = s;
        st[384 + tid] = (b2[tid] - m2[tid]) * s + be2[tid];
    }
}

// ---------------- FPS: one block/batch, 512 thr, u64-DPP reduce + ds_max_u64 ----------------
__global__ __launch_bounds__(512, 1) void fps_kernel(const float* __restrict__ xyz,
                                                     float* __restrict__ newxyz) {
    __shared__ float4 sxyz[NPTS];                       // 64 KB
    __shared__ unsigned long long kbuf[3];              // rotating global-max slots
    const int b    = blockIdx.x;
    const int tid  = threadIdx.x;
    const int lane = tid & 63;
    const float* xb = xyz + (size_t)b * NPTS * 3;

    v2f px[4], py[4], pz[4];
    float dd[8];
    unsigned invj[8];
#pragma unroll
    for (int i = 0; i < 8; ++i) {
        const int j = tid + i * 512;
        const float x = xb[3 * j], y = xb[3 * j + 1], z = xb[3 * j + 2];
        sxyz[j] = make_float4(x, y, z, 0.f);
        px[i >> 1][i & 1] = x;
        py[i >> 1][i & 1] = y;
        pz[i >> 1][i & 1] = z;
        dd[i] = 1e10f;
        invj[i] = 0xFFFFFFFFu - (unsigned)j;
    }
    if (tid < 3) kbuf[tid] = 0ull;

    float cx = xb[0], cy = xb[1], cz = xb[2];
    if (tid == 0) {
        float* o = newxyz + (size_t)b * NPOINT * 3;
        o[0] = cx; o[1] = cy; o[2] = cz;
    }
    __syncthreads();

    for (int t = 1; t < NPOINT; ++t) {
        // negated centroid: x + (-c) is bit-identical to x - c (IEEE RN)
        const v2f ncx = {-cx, -cx}, ncy = {-cy, -cy}, ncz = {-cz, -cz};
#pragma unroll
        for (int k = 0; k < 4; ++k) {
            v2f dx, dy, dz, qx, qy, qz, s1, s2;
            asm("v_pk_add_f32 %0, %1, %2" : "=v"(dx) : "v"(px[k]), "v"(ncx));
            asm("v_pk_add_f32 %0, %1, %2" : "=v"(dy) : "v"(py[k]), "v"(ncy));
            asm("v_pk_add_f32 %0, %1, %2" : "=v"(dz) : "v"(pz[k]), "v"(ncz));
            asm("v_pk_mul_f32 %0, %1, %1" : "=v"(qx) : "v"(dx));
            asm("v_pk_mul_f32 %0, %1, %1" : "=v"(qy) : "v"(dy));
            asm("v_pk_mul_f32 %0, %1, %1" : "=v"(qz) : "v"(dz));
            asm("v_pk_add_f32 %0, %1, %2" : "=v"(s1) : "v"(qx), "v"(qy));
            asm("v_pk_add_f32 %0, %1, %2" : "=v"(s2) : "v"(s1), "v"(qz));
            dd[2 * k]     = fminf(dd[2 * k],     s2[0]);
            dd[2 * k + 1] = fminf(dd[2 * k + 1], s2[1]);
        }
        // per-lane max over 8 slots
        const float m = fmaxf(fmaxf(fmaxf(dd[0], dd[1]), fmaxf(dd[2], dd[3])),
                              fmaxf(fmaxf(dd[4], dd[5]), fmaxf(dd[6], dd[7])));
        // first slot attaining m (descending scan => smallest i, i.e. smallest j wins)
        unsigned inv = invj[0];
#pragma unroll
        for (int i = 7; i >= 0; --i)
            if (dd[i] == m) inv = invj[i];
        // key: larger dist wins; tie -> larger ~j = smaller index (first-occurrence argmax)
        unsigned long long key =
            ((unsigned long long)__float_as_uint(m) << 32) | (unsigned long long)inv;
        // wave max -> lane 63 via u64 DPP ladder (index rides along; exact tie-break)
        key = ullmax(key, dpp_u64<0x111>(key));  // row_shr:1
        key = ullmax(key, dpp_u64<0x112>(key));  // row_shr:2
        key = ullmax(key, dpp_u64<0x114>(key));  // row_shr:4
        key = ullmax(key, dpp_u64<0x118>(key));  // row_shr:8
        key = ullmax(key, dpp_u64<0x142>(key));  // row_bcast:15
        key = ullmax(key, dpp_u64<0x143>(key));  // row_bcast:31
        if (lane == 63) atomicMax(&kbuf[t % 3], key);
        if (tid == 0) kbuf[(t + 1) % 3] = 0ull;   // reset for step t+1 (3-phase rotation)
        __syncthreads();

        const unsigned long long v = kbuf[t % 3];   // broadcast read
        const unsigned widx = 0xFFFFFFFFu - (unsigned)(v & 0xFFFFFFFFull);
        const float4 c = sxyz[widx];
        cx = c.x; cy = c.y; cz = c.z;
        if (tid == 0) {
            float* o = newxyz + ((size_t)b * NPOINT + t) * 3;
            o[0] = cx; o[1] = cy; o[2] = cz;
        }
    }
}

// ---------------- ball query: one wave per query ----------------
__global__ __launch_bounds__(256) void ballq_kernel(const float* __restrict__ xyz,
                                                    const float* __restrict__ newxyz,
                                                    int* __restrict__ gidx) {
    __shared__ int g[4][NSAMPLE];
    const int lane = threadIdx.x & 63;
    const int w    = threadIdx.x >> 6;
    const int q    = blockIdx.x * 4 + w;   // b*1024 + s
    const int b    = q >> 10;
    const float* xb = xyz + (size_t)b * NPTS * 3;
    const float* c  = newxyz + (size_t)q * 3;
    const float cx = c[0], cy = c[1], cz = c[2];
    const float r2 = 0.04f;

    int cnt = 0;
    for (int base = 0; base < NPTS; base += 64) {
        const int j = base + lane;
        const float d = sqdist_rn(xb[j * 3 + 0], xb[j * 3 + 1], xb[j * 3 + 2], cx, cy, cz);
        const bool keep = !(d > r2);
        const unsigned long long m = __ballot(keep);
        if (keep) {
            const int slot = cnt + __popcll(m & ((1ull << lane) - 1ull));
            if (slot < NSAMPLE) g[w][slot] = j;
        }
        cnt += (int)__popcll(m);
        if (cnt >= NSAMPLE) break;
    }
    __syncthreads();
    const int first = g[w][0];   // at least the center point itself is within radius
    if (lane < NSAMPLE) {
        const int v = (lane < cnt) ? g[w][lane] : first;
        gidx[(size_t)q * NSAMPLE + lane] = v;
    }
}

// ---------------- grouped MLP + maxpool: one wave per query ----------------
// Output-channel mapping for layers 0/1: lane oo, acc column j -> channel o = oo + 8j
// (weights/st pre-permuted in prep). LDS X row index always equals channel index.
__global__ __launch_bounds__(256) void mlp_kernel(
    const float* __restrict__ xyz, const float* __restrict__ points,
    const float* __restrict__ newxyz, const int* __restrict__ gidx,
    const float* __restrict__ wT0, const float* __restrict__ wT1,
    const float* __restrict__ wT2, const float* __restrict__ st,
    float* __restrict__ outp) {
    __shared__ float Xs[4][68][36];   // per-wave x, channel-major [c][k]
    const int lane = threadIdx.x & 63;
    const int w    = threadIdx.x >> 6;
    const int q    = blockIdx.x * 4 + w;
    const int b    = q >> 10;
    float (*X)[36] = Xs[w];
    const int* gi = gidx + (size_t)q * NSAMPLE;
    const float* nc = newxyz + (size_t)q * 3;
    const float c0 = nc[0], c1 = nc[1], c2 = nc[2];

    // gather: lane = channel, loop over samples; points row is 256B coalesced
    for (int k = 0; k < NSAMPLE; ++k) {
        const int idx = gi[k];
        X[3 + lane][k] = points[((size_t)b * NPTS + idx) * DCH + lane];
        if (lane < 3) {
            const float cv = (lane == 0) ? c0 : ((lane == 1) ? c1 : c2);
            X[lane][k] = xyz[((size_t)b * NPTS + idx) * 3 + lane] - cv;
        }
    }

    const int kk = lane >> 3;  // 4-sample tile
    const int oo = lane & 7;   // 8-out-channel tile

    // ---- layer 0: 67 -> 64
    float acc[4][8];
#pragma unroll
    for (int i = 0; i < 4; ++i)
#pragma unroll
        for (int j = 0; j < 8; ++j) acc[i][j] = 0.f;

    for (int c = 0; c < 67; ++c) {
        const float4 xv = *reinterpret_cast<const float4*>(&X[c][4 * kk]);
        const float4 wa = *reinterpret_cast<const float4*>(&wT0[c * 64 + 8 * oo]);
        const float4 wb = *reinterpret_cast<const float4*>(&wT0[c * 64 + 8 * oo + 4]);
        const float xr[4] = {xv.x, xv.y, xv.z, xv.w};
        const float wr[8] = {wa.x, wa.y, wa.z, wa.w, wb.x, wb.y, wb.z, wb.w};
#pragma unroll
        for (int i = 0; i < 4; ++i)
#pragma unroll
            for (int j = 0; j < 8; ++j)
                acc[i][j] = fmaf(xr[i], wr[j], acc[i][j]);
    }
    {
        const float4 sa = *reinterpret_cast<const float4*>(&st[8 * oo]);
        const float4 sb = *reinterpret_cast<const float4*>(&st[8 * oo + 4]);
        const float4 ta = *reinterpret_cast<const float4*>(&st[64 + 8 * oo]);
        const float4 tb = *reinterpret_cast<const float4*>(&st[64 + 8 * oo + 4]);
        const float sr[8] = {sa.x, sa.y, sa.z, sa.w, sb.x, sb.y, sb.z, sb.w};
        const float tr[8] = {ta.x, ta.y, ta.z, ta.w, tb.x, tb.y, tb.z, tb.w};
#pragma unroll
        for (int j = 0; j < 8; ++j) {
            float4 v;
            v.x = fmaxf(fmaf(acc[0][j], sr[j], tr[j]), 0.f);
            v.y = fmaxf(fmaf(acc[1][j], sr[j], tr[j]), 0.f);
            v.z = fmaxf(fmaf(acc[2][j], sr[j], tr[j]), 0.f);
            v.w = fmaxf(fmaf(acc[3][j], sr[j], tr[j]), 0.f);
            *reinterpret_cast<float4*>(&X[oo + 8 * j][4 * kk]) = v;  // channel oo+8j, conflict-free
        }
    }

    // ---- layer 1: 64 -> 64
#pragma unroll
    for (int i = 0; i < 4; ++i)
#pragma unroll
        for (int j = 0; j < 8; ++j) acc[i][j] = 0.f;

    for (int c = 0; c < 64; ++c) {
        const float4 xv = *reinterpret_cast<const float4*>(&X[c][4 * kk]);
        const float4 wa = *reinterpret_cast<const float4*>(&wT1[c * 64 + 8 * oo]);
        const float4 wb = *reinterpret_cast<const float4*>(&wT1[c * 64 + 8 * oo + 4]);
        const float xr[4] = {xv.x, xv.y, xv.z, xv.w};
        const float wr[8] = {wa.x, wa.y, wa.z, wa.w, wb.x, wb.y, wb.z, wb.w};
#pragma unroll
        for (int i = 0; i < 4; ++i)
#pragma unroll
            for (int j = 0; j < 8; ++j)
                acc[i][j] = fmaf(xr[i], wr[j], acc[i][j]);
    }
    {
        const float4 sa = *reinterpret_cast<const float4*>(&st[128 + 8 * oo]);
        const float4 sb = *reinterpret_cast<const float4*>(&st[128 + 8 * oo + 4]);
        const float4 ta = *reinterpret_cast<const float4*>(&st[192 + 8 * oo]);
        const float4 tb = *reinterpret_cast<const float4*>(&st[192 + 8 * oo + 4]);
        const float sr[8] = {sa.x, sa.y, sa.z, sa.w, sb.x, sb.y, sb.z, sb.w};
        const float tr[8] = {ta.x, ta.y, ta.z, ta.w, tb.x, tb.y, tb.z, tb.w};
#pragma unroll
        for (int j = 0; j < 8; ++j) {
            float4 v;
            v.x = fmaxf(fmaf(acc[0][j], sr[j], tr[j]), 0.f);
            v.y = fmaxf(fmaf(acc[1][j], sr[j], tr[j]), 0.f);
            v.z = fmaxf(fmaf(acc[2][j], sr[j], tr[j]), 0.f);
            v.w = fmaxf(fmaf(acc[3][j], sr[j], tr[j]), 0.f);
            *reinterpret_cast<float4*>(&X[oo + 8 * j][4 * kk]) = v;  // channel oo+8j
        }
    }

    // ---- layer 2: 64 -> 128, fused maxpool over k (unpermuted channel map 16oo+j)
    float a2[4][16];
#pragma unroll
    for (int i = 0; i < 4; ++i)
#pragma unroll
        for (int j = 0; j < 16; ++j) a2[i][j] = 0.f;

    for (int c = 0; c < 64; ++c) {
        const float4 xv = *reinterpret_cast<const float4*>(&X[c][4 * kk]);
        const float xr[4] = {xv.x, xv.y, xv.z, xv.w};
        float wr[16];
#pragma unroll
        for (int j4 = 0; j4 < 4; ++j4) {
            const float4 wv = *reinterpret_cast<const float4*>(&wT2[c * 128 + 16 * oo + 4 * j4]);
            wr[4 * j4 + 0] = wv.x; wr[4 * j4 + 1] = wv.y;
            wr[4 * j4 + 2] = wv.z; wr[4 * j4 + 3] = wv.w;
        }
#pragma unroll
        for (int i = 0; i < 4; ++i)
#pragma unroll
            for (int j = 0; j < 16; ++j)
                a2[i][j] = fmaf(xr[i], wr[j], a2[i][j]);
    }

    float mx[16];
#pragma unroll
    for (int j = 0; j < 16; ++j) {
        const float sj = st[256 + 16 * oo + j];
        const float tj = st[384 + 16 * oo + j];
        float mm = fmaxf(fmaf(a2[0][j], sj, tj), 0.f);
        mm = fmaxf(mm, fmaxf(fmaf(a2[1][j], sj, tj), 0.f));
        mm = fmaxf(mm, fmaxf(fmaf(a2[2][j], sj, tj), 0.f));
        mm = fmaxf(mm, fmaxf(fmaf(a2[3][j], sj, tj), 0.f));
        mx[j] = mm;
    }
#pragma unroll
    for (int j = 0; j < 16; ++j) {
        mx[j] = fmaxf(mx[j], __shfl_xor(mx[j], 8, 64));
        mx[j] = fmaxf(mx[j], __shfl_xor(mx[j], 16, 64));
        mx[j] = fmaxf(mx[j], __shfl_xor(mx[j], 32, 64));
    }
    if (kk == 0) {
        float* dst = outp + (size_t)q * 128 + 16 * oo;
#pragma unroll
        for (int j4 = 0; j4 < 4; ++j4) {
            float4 v;
            v.x = mx[4 * j4 + 0]; v.y = mx[4 * j4 + 1];
            v.z = mx[4 * j4 + 2]; v.w = mx[4 * j4 + 3];
            *reinterpret_cast<float4*>(&dst[4 * j4]) = v;
        }
    }
}

extern "C" void kernel_launch(void* const* d_in, const int* in_sizes, int n_in,
                              void* d_out, int out_size, void* d_ws, size_t ws_size,
                              hipStream_t stream) {
    const float* xyz    = (const float*)d_in[0];
    const float* points = (const float*)d_in[1];
    const float* w0  = (const float*)d_in[2];
    const float* b0  = (const float*)d_in[3];
    const float* g0  = (const float*)d_in[4];
    const float* be0 = (const float*)d_in[5];
    const float* m0  = (const float*)d_in[6];
    const float* v0  = (const float*)d_in[7];
    const float* w1  = (const float*)d_in[8];
    const float* b1  = (const float*)d_in[9];
    const float* g1  = (const float*)d_in[10];
    const float* be1 = (const float*)d_in[11];
    const float* m1  = (const float*)d_in[12];
    const float* v1  = (const float*)d_in[13];
    const float* w2  = (const float*)d_in[14];
    const float* b2  = (const float*)d_in[15];
    const float* g2  = (const float*)d_in[16];
    const float* be2 = (const float*)d_in[17];
    const float* m2  = (const float*)d_in[18];
    const float* v2  = (const float*)d_in[19];

    float* out = (float*)d_out;
    float* ws  = (float*)d_ws;
    float* wT0 = ws;            // 67*64  = 4288
    float* wT1 = ws + 4288;     // 64*64  = 4096
    float* wT2 = ws + 8384;     // 64*128 = 8192
    float* st  = ws + 16576;    // 512 (s0,t0,s1,t1,s2,t2)
    int*   gidx = (int*)(ws + 17088);  // 8192*32 ints

    prep_kernel<<<dim3(17), dim3(256), 0, stream>>>(w0, b0, g0, be0, m0, v0,
                                                    w1, b1, g1, be1, m1, v1,
                                                    w2, b2, g2, be2, m2, v2,
                                                    wT0, wT1, wT2, st);
    fps_kernel<<<dim3(BATCH), dim3(512), 0, stream>>>(xyz, out);
    ballq_kernel<<<dim3(2048), dim3(256), 0, stream>>>(xyz, out, gidx);
    mlp_kernel<<<dim3(2048), dim3(256), 0, stream>>>(xyz, points, out, gidx,
                                                     wT0, wT1, wT2, st,
                                                     out + NEWXYZ_FLOATS);
}